// Round 11
// baseline (379.092 us; speedup 1.0000x reference)
//
#include <hip/hip_runtime.h>
#include <math.h>

#define CAP 64

typedef __attribute__((ext_vector_type(8))) short short8;
typedef __attribute__((ext_vector_type(4))) float f32x4;

__device__ __forceinline__ float lrelu02(float v) { return v > 0.f ? v : 0.2f * v; }
__device__ __forceinline__ float lrelu01(float v) { return v > 0.f ? v : 0.01f * v; }

__device__ __forceinline__ float bfl(unsigned u) { return __uint_as_float(u << 16); }
__device__ __forceinline__ float bfh(unsigned u) { return __uint_as_float(u & 0xffff0000u); }
__device__ __forceinline__ unsigned short f2bf(float f) {
  unsigned u = __float_as_uint(f);
  return (unsigned short)((u + 0x7fffu + ((u >> 16) & 1u)) >> 16);  // RNE
}
__device__ __forceinline__ unsigned pk2bf(float lo, float hi) {
  return (unsigned)f2bf(lo) | ((unsigned)f2bf(hi) << 16);
}

// ---------------- prep: CSR fill (dst-range partitioned) + weight transposes, one launch ----------------
__global__ __launch_bounds__(256) void prep_k(const int* __restrict__ ei, int* __restrict__ deg,
                                              unsigned short* __restrict__ cols, int E, int nr, int Nn,
                                              const float* __restrict__ W1, const float* __restrict__ W2,
                                              const float* __restrict__ Wl,
                                              unsigned short* __restrict__ t1, unsigned short* __restrict__ t2,
                                              unsigned short* __restrict__ tl) {
  if (blockIdx.x < 2048) {
    const int r = blockIdx.x & 7;
    const int c = blockIdx.x >> 3;
    const unsigned lo = (unsigned)(r * nr);
    const unsigned hi = (unsigned)min(Nn, (r + 1) * nr);
    const int chunk = (E + 255) >> 8;
    const int e0 = c * chunk;
    const int e1 = min(E, e0 + chunk);
    for (int e = e0 + (int)threadIdx.x; e < e1; e += 256) {
      unsigned d = (unsigned)ei[E + e];
      if (d >= lo && d < hi) {
        int s = ei[e];
        int pos = atomicAdd(&deg[d], 1);
        if (pos < CAP) cols[(size_t)d * CAP + pos] = (unsigned short)s;
      }
    }
  } else {
    int b = blockIdx.x - 2048, tid = threadIdx.x;
    const float* src; unsigned short* dst; int K, NC, base;
    if (b < 64)       { src = W1; dst = t1; K = 128; NC = 128; base = 0; }
    else if (b < 128) { src = W2; dst = t2; K = 128; NC = 128; base = 64; }
    else              { src = Wl; dst = tl; K = 128; NC = 32;  base = 128; }
    int e = (b - base) * 256 + tid;
    if (e < K * NC) {
      int k = e / NC, c2 = e - k * NC;
      dst[c2 * K + k] = f2bf(src[e]);
    }
  }
}

// ---------------- MFMA bf16 GEMM: C[M,NC] = A[M,K] @ W[K,NC] ----------------
template<int K, int NC, bool ALPHA, bool IN32>
__global__ __launch_bounds__(256) void gemm_mfma(const void* __restrict__ Av,
                                                 const unsigned short* __restrict__ Wt,
                                                 unsigned short* __restrict__ Cb,
                                                 const float* __restrict__ a_s, const float* __restrict__ a_d,
                                                 float* __restrict__ asrc, float* __restrict__ adst, int M) {
  constexpr int BM = (NC == 128) ? 64 : 128;
  constexpr int NKS = K / 32;
  constexpr int RS = (NC == 128) ? 4 : 2;
  constexpr int SWZ = 7;
  constexpr int CH = BM * K / 2048;
  __shared__ unsigned short At[BM * K];
  const int tid = threadIdx.x;
  const int wid = tid >> 6, lane = tid & 63;
  const int g = lane >> 4, l15 = lane & 15;
  const int row0 = blockIdx.x * BM;

  short8 wf[NKS][2];
  const int cglob0 = ((NC == 128) ? 32 * wid : 0) + l15;
#pragma unroll
  for (int ks = 0; ks < NKS; ++ks)
#pragma unroll
    for (int cf = 0; cf < 2; ++cf)
      wf[ks][cf] = *(const short8*)(Wt + (size_t)(cglob0 + 16 * cf) * K + ks * 32 + g * 8);

  uint4 ra[CH];
  if constexpr (IN32) {
    const float* Af = (const float*)Av;
#pragma unroll
    for (int c = 0; c < CH; ++c) {
      int ch = c * 256 + tid;
      int row = ch * 8 / K;
      int col = ch * 8 - row * K;
      float4 lo = {0.f, 0.f, 0.f, 0.f}, hi = {0.f, 0.f, 0.f, 0.f};
      if (row0 + row < M) {
        lo = *(const float4*)(Af + (size_t)(row0 + row) * K + col);
        hi = *(const float4*)(Af + (size_t)(row0 + row) * K + col + 4);
      }
      ra[c] = make_uint4(pk2bf(lo.x, lo.y), pk2bf(lo.z, lo.w), pk2bf(hi.x, hi.y), pk2bf(hi.z, hi.w));
    }
  } else {
    const unsigned short* Ab = (const unsigned short*)Av;
#pragma unroll
    for (int c = 0; c < CH; ++c) {
      int ch = c * 256 + tid;
      int row = ch * 8 / K;
      ra[c] = (row0 + row < M) ? *(const uint4*)(Ab + (size_t)row0 * K + ch * 8)
                               : make_uint4(0u, 0u, 0u, 0u);
    }
  }
#pragma unroll
  for (int c = 0; c < CH; ++c) {
    int ch = c * 256 + tid;
    int row = ch * 8 / K;
    int off = ch * 16 - row * (2 * K);
    *(uint4*)((char*)At + row * (2 * K) + (off ^ ((row & SWZ) << 4))) = ra[c];
  }
  __syncthreads();

  f32x4 acc[RS][2];
#pragma unroll
  for (int r = 0; r < RS; ++r)
#pragma unroll
    for (int cf = 0; cf < 2; ++cf) acc[r][cf] = (f32x4){0.f, 0.f, 0.f, 0.f};

  const int rwave = (NC == 128) ? 0 : 32 * wid;
#pragma unroll
  for (int ks = 0; ks < NKS; ++ks) {
#pragma unroll
    for (int r = 0; r < RS; ++r) {
      int row = rwave + 16 * r + l15;
      int off = ks * 64 + g * 16;
      short8 af = *(const short8*)((const char*)At + row * (2 * K) + (off ^ ((row & SWZ) << 4)));
#pragma unroll
      for (int cf = 0; cf < 2; ++cf)
        acc[r][cf] = __builtin_amdgcn_mfma_f32_16x16x32_bf16(wf[ks][cf], af, acc[r][cf], 0, 0, 0);
    }
  }

#pragma unroll
  for (int r = 0; r < RS; ++r) {
    const int row = row0 + rwave + 16 * r + l15;
    const bool ok = row < M;
#pragma unroll
    for (int cf = 0; cf < 2; ++cf) {
      const int colbase = ((NC == 128) ? 32 * wid : 0) + 16 * cf + 4 * g;
      if (ok) {
        ushort4 o;
        o.x = f2bf(acc[r][cf][0]); o.y = f2bf(acc[r][cf][1]);
        o.z = f2bf(acc[r][cf][2]); o.w = f2bf(acc[r][cf][3]);
        *(ushort4*)(Cb + (size_t)row * NC + colbase) = o;
      }
    }
    if constexpr (ALPHA) {
      constexpr int H = NC / 32;
      const int head = (NC == 128) ? wid : 0;
      float ps = 0.f, pd = 0.f;
#pragma unroll
      for (int cf = 0; cf < 2; ++cf) {
        float4 sa = *(const float4*)(a_s + head * 32 + 16 * cf + 4 * g);
        float4 da = *(const float4*)(a_d + head * 32 + 16 * cf + 4 * g);
        ps += acc[r][cf][0] * sa.x + acc[r][cf][1] * sa.y + acc[r][cf][2] * sa.z + acc[r][cf][3] * sa.w;
        pd += acc[r][cf][0] * da.x + acc[r][cf][1] * da.y + acc[r][cf][2] * da.z + acc[r][cf][3] * da.w;
      }
      ps += __shfl_xor(ps, 16, 64); pd += __shfl_xor(pd, 16, 64);
      ps += __shfl_xor(ps, 32, 64); pd += __shfl_xor(pd, 32, 64);
      if (g == 0 && ok) {
        asrc[(size_t)row * H + head] = ps;
        adst[(size_t)row * H + head] = pd;
      }
    }
  }
}

// ---------------- agg for HC=128 (H=4): one wave per node ----------------
template<int ACT>
__global__ __launch_bounds__(256) void agg128_k(const unsigned short* __restrict__ Hb,
                                                const float* __restrict__ asrc,
                                                const float* __restrict__ adst,
                                                const int* __restrict__ deg,
                                                const unsigned short* __restrict__ cols,
                                                const float* __restrict__ bias,
                                                unsigned short* __restrict__ Y, int Nn) {
  __shared__ float wl[4][256];
  __shared__ int sl[4][64];
  const int wid = threadIdx.x >> 6, lane = threadIdx.x & 63;
  const int node = blockIdx.x * 4 + wid;
  if (node >= Nn) return;
  const int eidx = lane >> 2, h4 = lane & 3;
  const float adr = adst[node * 4 + h4];
  const float asr = asrc[node * 4 + h4];
  int cnt = deg[node];
  cnt = cnt > CAP ? CAP : cnt;
  const unsigned short* __restrict__ cl = cols + (size_t)node * CAP;
  float dn = 0.f;
  for (int c0 = 0; c0 < cnt; c0 += 16) {
    int e = c0 + eidx;
    bool valid = e < cnt;
    int s = valid ? (int)cl[e] : 0;
    float w = valid ? __expf(lrelu02(asrc[s * 4 + h4] + adr)) : 0.f;
    wl[wid][e * 4 + h4] = w;
    if (h4 == 0) sl[wid][e] = s * 16;
    dn += w;
  }
  dn += __shfl_xor(dn, 4, 64);
  dn += __shfl_xor(dn, 8, 64);
  dn += __shfl_xor(dn, 16, 64);
  dn += __shfl_xor(dn, 32, 64);
  float wself = __expf(lrelu02(asr + adr));
  dn += wself;
  float inv = 1.f / (dn + 1e-16f);
  float wsinv = wself * inv;
  for (int j = lane; j < cnt * 4; j += 64) wl[wid][j] *= inv;
  float wns = __shfl(wsinv, (lane & 15) >> 2, 64);
  __builtin_amdgcn_wave_barrier();

  const uint4* __restrict__ HB = (const uint4*)Hb;
  const int sub = lane >> 4;
  const int c8 = lane & 15;
  const int h = c8 >> 2;
  float a0 = 0.f, a1 = 0.f, a2 = 0.f, a3 = 0.f, a4 = 0.f, a5 = 0.f, a6 = 0.f, a7 = 0.f;
  float p0 = 0.f, p1 = 0.f, p2 = 0.f, p3 = 0.f, p4 = 0.f, p5 = 0.f, p6 = 0.f, p7 = 0.f;
  int i = sub;
  for (; i + 4 < cnt; i += 8) {
    int o0 = sl[wid][i];
    int o1 = sl[wid][i + 4];
    float w0 = wl[wid][i * 4 + h];
    float w1 = wl[wid][(i + 4) * 4 + h];
    uint4 u0 = HB[o0 + c8];
    uint4 u1 = HB[o1 + c8];
    a0 += w0 * bfl(u0.x); a1 += w0 * bfh(u0.x); a2 += w0 * bfl(u0.y); a3 += w0 * bfh(u0.y);
    a4 += w0 * bfl(u0.z); a5 += w0 * bfh(u0.z); a6 += w0 * bfl(u0.w); a7 += w0 * bfh(u0.w);
    p0 += w1 * bfl(u1.x); p1 += w1 * bfh(u1.x); p2 += w1 * bfl(u1.y); p3 += w1 * bfh(u1.y);
    p4 += w1 * bfl(u1.z); p5 += w1 * bfh(u1.z); p6 += w1 * bfl(u1.w); p7 += w1 * bfh(u1.w);
  }
  for (; i < cnt; i += 4) {
    int o0 = sl[wid][i];
    float w0 = wl[wid][i * 4 + h];
    uint4 u0 = HB[o0 + c8];
    a0 += w0 * bfl(u0.x); a1 += w0 * bfh(u0.x); a2 += w0 * bfl(u0.y); a3 += w0 * bfh(u0.y);
    a4 += w0 * bfl(u0.z); a5 += w0 * bfh(u0.z); a6 += w0 * bfl(u0.w); a7 += w0 * bfh(u0.w);
  }
  a0 += p0; a1 += p1; a2 += p2; a3 += p3; a4 += p4; a5 += p5; a6 += p6; a7 += p7;
#pragma unroll
  for (int off = 16; off <= 32; off <<= 1) {
    a0 += __shfl_xor(a0, off, 64); a1 += __shfl_xor(a1, off, 64);
    a2 += __shfl_xor(a2, off, 64); a3 += __shfl_xor(a3, off, 64);
    a4 += __shfl_xor(a4, off, 64); a5 += __shfl_xor(a5, off, 64);
    a6 += __shfl_xor(a6, off, 64); a7 += __shfl_xor(a7, off, 64);
  }
  if (lane < 16) {
    uint4 us = HB[node * 16 + c8];
    float4 b0 = *(const float4*)(bias + c8 * 8);
    float4 b1 = *(const float4*)(bias + c8 * 8 + 4);
    float o0 = a0 + wns * bfl(us.x) + b0.x;
    float o1 = a1 + wns * bfh(us.x) + b0.y;
    float o2 = a2 + wns * bfl(us.y) + b0.z;
    float o3 = a3 + wns * bfh(us.y) + b0.w;
    float o4 = a4 + wns * bfl(us.z) + b1.x;
    float o5 = a5 + wns * bfh(us.z) + b1.y;
    float o6 = a6 + wns * bfl(us.w) + b1.z;
    float o7 = a7 + wns * bfh(us.w) + b1.w;
    if (ACT == 1) {
      o0 = lrelu01(o0); o1 = lrelu01(o1); o2 = lrelu01(o2); o3 = lrelu01(o3);
      o4 = lrelu01(o4); o5 = lrelu01(o5); o6 = lrelu01(o6); o7 = lrelu01(o7);
    }
    ((uint4*)Y)[(size_t)node * 16 + c8] =
        make_uint4(pk2bf(o0, o1), pk2bf(o2, o3), pk2bf(o4, o5), pk2bf(o6, o7));
  }
}

// ---------------- agg32 core: phase 0+1, returns float4 of channels [4c,4c+4) valid on lanes<8 ----------------
template<int ACT>
__device__ __forceinline__ float4 agg32_core(const unsigned short* __restrict__ Hb,
                                             const float* __restrict__ asrc, const float* __restrict__ adst,
                                             const int* __restrict__ deg,
                                             const unsigned short* __restrict__ cols,
                                             const float* __restrict__ bias,
                                             float (*wl)[64], int (*sl)[64],
                                             int wid, int lane, int node) {
  const float adr = adst[node], asr = asrc[node];
  int cnt = deg[node];
  cnt = cnt > CAP ? CAP : cnt;
  const unsigned short* __restrict__ cl = cols + (size_t)node * CAP;
  int s = (lane < cnt) ? (int)cl[lane] : 0;
  float w = (lane < cnt) ? __expf(lrelu02(asrc[s] + adr)) : 0.f;
  float dn = w;
#pragma unroll
  for (int off = 32; off >= 1; off >>= 1) dn += __shfl_xor(dn, off, 64);
  float ws = __expf(lrelu02(asr + adr));
  dn += ws;
  float inv = 1.f / (dn + 1e-16f);
  wl[wid][lane] = w * inv;
  sl[wid][lane] = s * 8;
  __builtin_amdgcn_wave_barrier();

  const uint2* __restrict__ HB = (const uint2*)Hb;
  const int sub = lane >> 3;
  const int c = lane & 7;
  float a0 = 0.f, a1 = 0.f, a2 = 0.f, a3 = 0.f;
  float p0 = 0.f, p1 = 0.f, p2 = 0.f, p3 = 0.f;
  int i = sub;
  for (; i + 8 < cnt; i += 16) {
    int o0 = sl[wid][i];
    int o1 = sl[wid][i + 8];
    float w0 = wl[wid][i];
    float w1 = wl[wid][i + 8];
    uint2 u0 = HB[o0 + c];
    uint2 u1 = HB[o1 + c];
    a0 += w0 * bfl(u0.x); a1 += w0 * bfh(u0.x); a2 += w0 * bfl(u0.y); a3 += w0 * bfh(u0.y);
    p0 += w1 * bfl(u1.x); p1 += w1 * bfh(u1.x); p2 += w1 * bfl(u1.y); p3 += w1 * bfh(u1.y);
  }
  for (; i < cnt; i += 8) {
    int o0 = sl[wid][i];
    float w0 = wl[wid][i];
    uint2 u0 = HB[o0 + c];
    a0 += w0 * bfl(u0.x); a1 += w0 * bfh(u0.x); a2 += w0 * bfl(u0.y); a3 += w0 * bfh(u0.y);
  }
  a0 += p0; a1 += p1; a2 += p2; a3 += p3;
#pragma unroll
  for (int off = 8; off <= 32; off <<= 1) {
    a0 += __shfl_xor(a0, off, 64); a1 += __shfl_xor(a1, off, 64);
    a2 += __shfl_xor(a2, off, 64); a3 += __shfl_xor(a3, off, 64);
  }
  float4 out = make_float4(0.f, 0.f, 0.f, 0.f);
  if (lane < 8) {
    uint2 us = HB[node * 8 + c];
    float wns = ws * inv;
    float4 bb = ((const float4*)bias)[c];
    out.x = a0 + wns * bfl(us.x) + bb.x;
    out.y = a1 + wns * bfh(us.x) + bb.y;
    out.z = a2 + wns * bfl(us.y) + bb.z;
    out.w = a3 + wns * bfh(us.y) + bb.w;
    if (ACT == 1) { out.x = lrelu01(out.x); out.y = lrelu01(out.y); out.z = lrelu01(out.z); out.w = lrelu01(out.w); }
  }
  return out;
}

#define NODES_PER_BLK 64

// ---------------- agg32-L3 fused (node-looping, reg-held Wd): z; h4 = z@Wd; alphas4 ----------------
__global__ __launch_bounds__(256) void agg32_l3_k(const unsigned short* __restrict__ Hb,
                                                  const float* __restrict__ asrc, const float* __restrict__ adst,
                                                  const int* __restrict__ deg,
                                                  const unsigned short* __restrict__ cols,
                                                  const float* __restrict__ bl,
                                                  const float* __restrict__ Wd,
                                                  const float* __restrict__ ads, const float* __restrict__ add_,
                                                  float* __restrict__ zout, unsigned short* __restrict__ H4,
                                                  float* __restrict__ asrcB, float* __restrict__ adstB, int Nn) {
  __shared__ float wl[4][64];
  __shared__ int sl[4][64];
  __shared__ float zb[4][32];
  const int wid = threadIdx.x >> 6, lane = threadIdx.x & 63;
  const int j = lane & 31;
  // Wd column j in registers (once per block; L2-resident)
  float wdreg[32];
#pragma unroll
  for (int k = 0; k < 32; ++k) wdreg[k] = Wd[k * 32 + j];
  const float aj_s = ads[j], aj_d = add_[j];
  const int c = lane & 7;

  const int node0 = blockIdx.x * NODES_PER_BLK;
  const int nodeEnd = min(Nn, node0 + NODES_PER_BLK);
  for (int node = node0 + wid; node < nodeEnd; node += 4) {
    float4 z = agg32_core<0>(Hb, asrc, adst, deg, cols, bl, wl, sl, wid, lane, node);
    if (lane < 8) {
      ((float4*)zout)[(size_t)node * 8 + c] = z;
      *(float4*)&zb[wid][c * 4] = z;
    }
    __builtin_amdgcn_wave_barrier();
    float h4 = 0.f;
#pragma unroll
    for (int k = 0; k < 32; ++k) h4 += zb[wid][k] * wdreg[k];
    float ps = h4 * aj_s, pd = h4 * aj_d;
#pragma unroll
    for (int off = 1; off <= 16; off <<= 1) { ps += __shfl_xor(ps, off, 64); pd += __shfl_xor(pd, off, 64); }
    if (lane < 32) H4[(size_t)node * 32 + j] = f2bf(h4);
    if (lane == 0) {
      asrcB[node] = ps;
      adstB[node] = pd;
    }
  }
}

// ---------------- agg32-L4 fused (node-looping, reg-held Wdec): xr; rec = xr@Wdec + bdec + x ----------------
__global__ __launch_bounds__(256) void agg32_l4_k(const unsigned short* __restrict__ Hb,
                                                  const float* __restrict__ asrc, const float* __restrict__ adst,
                                                  const int* __restrict__ deg,
                                                  const unsigned short* __restrict__ cols,
                                                  const float* __restrict__ bd,
                                                  const float* __restrict__ Wdec,
                                                  const float* __restrict__ bdec,
                                                  const float* __restrict__ x,
                                                  float* __restrict__ rec, int Nn) {
  __shared__ float wl[4][64];
  __shared__ int sl[4][64];
  __shared__ float xb[4][32];
  const int wid = threadIdx.x >> 6, lane = threadIdx.x & 63;
  // Wdec columns (lane, lane+64) in registers (once per block; L2-resident)
  float wreg0[32], wreg1[32];
#pragma unroll
  for (int k = 0; k < 32; ++k) {
    wreg0[k] = Wdec[k * 128 + lane];
    wreg1[k] = Wdec[k * 128 + lane + 64];
  }
  const float bd0 = bdec[lane], bd1 = bdec[lane + 64];
  const int c = lane & 7;

  const int node0 = blockIdx.x * NODES_PER_BLK;
  const int nodeEnd = min(Nn, node0 + NODES_PER_BLK);
  for (int node = node0 + wid; node < nodeEnd; node += 4) {
    float4 xr = agg32_core<1>(Hb, asrc, adst, deg, cols, bd, wl, sl, wid, lane, node);
    if (lane < 8) *(float4*)&xb[wid][c * 4] = xr;
    __builtin_amdgcn_wave_barrier();
    float r0 = 0.f, r1 = 0.f;
#pragma unroll
    for (int k = 0; k < 32; ++k) {
      float xv = xb[wid][k];
      r0 += xv * wreg0[k];
      r1 += xv * wreg1[k];
    }
    r0 += bd0 + x[(size_t)node * 128 + lane];
    r1 += bd1 + x[(size_t)node * 128 + lane + 64];
    rec[(size_t)node * 128 + lane] = r0;
    rec[(size_t)node * 128 + lane + 64] = r1;
  }
}

extern "C" void kernel_launch(void* const* d_in, const int* in_sizes, int n_in,
                              void* d_out, int out_size, void* d_ws, size_t ws_size,
                              hipStream_t stream) {
  const float* x = (const float*)d_in[0];
  const int* ei = (const int*)d_in[1];
  const float* W1 = (const float*)d_in[2];
  const float* a1s = (const float*)d_in[3];
  const float* a1d = (const float*)d_in[4];
  const float* b1 = (const float*)d_in[5];
  const float* W2 = (const float*)d_in[6];
  const float* a2s = (const float*)d_in[7];
  const float* a2d = (const float*)d_in[8];
  const float* b2 = (const float*)d_in[9];
  const float* Wl = (const float*)d_in[10];
  const float* als = (const float*)d_in[11];
  const float* ald = (const float*)d_in[12];
  const float* bl = (const float*)d_in[13];
  const float* Wd = (const float*)d_in[14];
  const float* ads = (const float*)d_in[15];
  const float* add_ = (const float*)d_in[16];
  const float* bd = (const float*)d_in[17];
  const float* Wdec = (const float*)d_in[18];
  const float* bdec = (const float*)d_in[19];

  const int N = in_sizes[0] / 128;
  const int E = in_sizes[1] / 2;
  const int nr = (N + 7) / 8;

  char* ws = (char*)d_ws;
  auto alloc = [&](size_t bytes) {
    char* p = ws;
    ws += (bytes + 255) & ~(size_t)255;
    return p;
  };
  unsigned short* cols = (unsigned short*)alloc((size_t)N * CAP * 2);
  int* deg = (int*)alloc((size_t)N * 4);
  unsigned short* hb16 = (unsigned short*)alloc((size_t)N * 128 * 2);
  float* asrc = (float*)alloc((size_t)N * 4 * 4);
  float* adst = (float*)alloc((size_t)N * 4 * 4);
  float* asrcB = (float*)alloc((size_t)N * 4);
  float* adstB = (float*)alloc((size_t)N * 4);
  unsigned short* x12 = (unsigned short*)alloc((size_t)N * 128 * 2);  // x1, then x2 (aliased)
  unsigned short* hb2 = (unsigned short*)alloc((size_t)N * 32 * 2);   // h4
  unsigned short* W1t = (unsigned short*)alloc(128 * 128 * 2);
  unsigned short* W2t = (unsigned short*)alloc(128 * 128 * 2);
  unsigned short* Wlt = (unsigned short*)alloc(128 * 32 * 2);

  float* rec = (float*)d_out;                     // [N,128]
  float* zout = (float*)d_out + (size_t)N * 128;  // [N,32]

  hipMemsetAsync(deg, 0, (size_t)N * 4, stream);
  prep_k<<<2192, 256, 0, stream>>>(ei, deg, cols, E, nr, N, W1, W2, Wl, W1t, W2t, Wlt);

  const int gG128 = (N + 63) / 64;   // BM=64 grids (NC=128)
  const int gG32 = (N + 127) / 128;  // BM=128 grids (NC=32)
  const int gAg = (N + 3) / 4;
  const int gF = (N + NODES_PER_BLK - 1) / NODES_PER_BLK;

  // Layer 1: x(fp32, converted in staging) -> h1(bf16) + alphas; agg -> x1(bf16)
  gemm_mfma<128, 128, true, true><<<gG128, 256, 0, stream>>>(
      x, W1t, hb16, a1s, a1d, asrc, adst, N);
  agg128_k<1><<<gAg, 256, 0, stream>>>(hb16, asrc, adst, deg, cols, b1, x12, N);

  // Layer 2: x1 -> h2 + alphas; agg -> x2 (in-place over x1)
  gemm_mfma<128, 128, true, false><<<gG128, 256, 0, stream>>>(
      x12, W2t, hb16, a2s, a2d, asrc, adst, N);
  agg128_k<1><<<gAg, 256, 0, stream>>>(hb16, asrc, adst, deg, cols, b2, x12, N);

  // Layer 3 (latent): x2 -> h3 + alphas
  gemm_mfma<128, 32, true, false><<<gG32, 256, 0, stream>>>(
      x12, Wlt, hb16, als, ald, asrc, adst, N);
  // agg -> z (fp32 to d_out); fused: h4 = z@Wd (f32) + L4 alphas, h4 -> bf16
  agg32_l3_k<<<gF, 256, 0, stream>>>(hb16, asrc, adst, deg, cols, bl, Wd, ads, add_,
                                     zout, hb2, asrcB, adstB, N);
  // Layer 4 + decode fused: gather h4 -> xr; rec = xr@Wdec + bdec + x
  agg32_l4_k<<<gF, 256, 0, stream>>>(hb2, asrcB, adstB, deg, cols, bd, Wdec, bdec, x, rec, N);
}

// Round 12
// 328.109 us; speedup vs baseline: 1.1554x; 1.1554x over previous
//
#include <hip/hip_runtime.h>
#include <math.h>

#define CAP 64

typedef __attribute__((ext_vector_type(8))) short short8;
typedef __attribute__((ext_vector_type(4))) float f32x4;

__device__ __forceinline__ float lrelu02(float v) { return v > 0.f ? v : 0.2f * v; }
__device__ __forceinline__ float lrelu01(float v) { return v > 0.f ? v : 0.01f * v; }

__device__ __forceinline__ float bfl(unsigned u) { return __uint_as_float(u << 16); }
__device__ __forceinline__ float bfh(unsigned u) { return __uint_as_float(u & 0xffff0000u); }
__device__ __forceinline__ unsigned short f2bf(float f) {
  unsigned u = __float_as_uint(f);
  return (unsigned short)((u + 0x7fffu + ((u >> 16) & 1u)) >> 16);  // RNE
}
__device__ __forceinline__ unsigned pk2bf(float lo, float hi) {
  return (unsigned)f2bf(lo) | ((unsigned)f2bf(hi) << 16);
}

// ---------------- prep: CSR fill (dst-range partitioned, XCD-local atomics) + weight transposes ----------------
__global__ __launch_bounds__(256) void prep_k(const int* __restrict__ ei, int* __restrict__ deg,
                                              unsigned short* __restrict__ cols, int E, int nr, int Nn,
                                              const float* __restrict__ W1, const float* __restrict__ W2,
                                              const float* __restrict__ Wl,
                                              unsigned short* __restrict__ t1, unsigned short* __restrict__ t2,
                                              unsigned short* __restrict__ tl) {
  if (blockIdx.x < 2048) {
    const int r = blockIdx.x & 7;
    const int c = blockIdx.x >> 3;
    const unsigned lo = (unsigned)(r * nr);
    const unsigned hi = (unsigned)min(Nn, (r + 1) * nr);
    const int chunk = (E + 255) >> 8;
    const int e0 = c * chunk;
    const int e1 = min(E, e0 + chunk);
    for (int e = e0 + (int)threadIdx.x; e < e1; e += 256) {
      unsigned d = (unsigned)ei[E + e];
      if (d >= lo && d < hi) {
        int s = ei[e];
        int pos = atomicAdd(&deg[d], 1);
        if (pos < CAP) cols[(size_t)d * CAP + pos] = (unsigned short)s;
      }
    }
  } else {
    int b = blockIdx.x - 2048, tid = threadIdx.x;
    const float* src; unsigned short* dst; int K, NC, base;
    if (b < 64)       { src = W1; dst = t1; K = 128; NC = 128; base = 0; }
    else if (b < 128) { src = W2; dst = t2; K = 128; NC = 128; base = 64; }
    else              { src = Wl; dst = tl; K = 128; NC = 32;  base = 128; }
    int e = (b - base) * 256 + tid;
    if (e < K * NC) {
      int k = e / NC, c2 = e - k * NC;
      dst[c2 * K + k] = f2bf(src[e]);
    }
  }
}

// ---------------- MFMA bf16 GEMM: C[M,NC] = A[M,K] @ W[K,NC] ----------------
// Wt bf16 transposed [NC][K]. mfma(Wfrag, Afrag, acc): row = lane&15, 4 cols/lane.
// NC=128: BM=64, wave w owns cols [32w,32w+32). NC=32: BM=128, wave w rows [32w,32w+32).
template<int K, int NC, bool OUT16, bool ALPHA, bool RB, bool IN32>
__global__ __launch_bounds__(256) void gemm_mfma(const void* __restrict__ Av,
                                                 const unsigned short* __restrict__ Wt,
                                                 const float* __restrict__ bias,
                                                 const float* __restrict__ resid,
                                                 void* __restrict__ Cv,
                                                 const float* __restrict__ a_s, const float* __restrict__ a_d,
                                                 float* __restrict__ asrc, float* __restrict__ adst, int M) {
  constexpr int BM = (NC == 128) ? 64 : 128;
  constexpr int NKS = K / 32;
  constexpr int RS = (NC == 128) ? 4 : 2;
  constexpr int SWZ = (K == 128) ? 7 : 3;
  constexpr int CH = BM * K / 2048;
  __shared__ unsigned short At[BM * K];
  const int tid = threadIdx.x;
  const int wid = tid >> 6, lane = tid & 63;
  const int g = lane >> 4, l15 = lane & 15;
  const int row0 = blockIdx.x * BM;

  short8 wf[NKS][2];
  const int cglob0 = ((NC == 128) ? 32 * wid : 0) + l15;
#pragma unroll
  for (int ks = 0; ks < NKS; ++ks)
#pragma unroll
    for (int cf = 0; cf < 2; ++cf)
      wf[ks][cf] = *(const short8*)(Wt + (size_t)(cglob0 + 16 * cf) * K + ks * 32 + g * 8);

  uint4 ra[CH];
  if constexpr (IN32) {
    const float* Af = (const float*)Av;
#pragma unroll
    for (int c = 0; c < CH; ++c) {
      int ch = c * 256 + tid;
      int row = ch * 8 / K;
      int col = ch * 8 - row * K;
      float4 lo = {0.f, 0.f, 0.f, 0.f}, hi = {0.f, 0.f, 0.f, 0.f};
      if (row0 + row < M) {
        lo = *(const float4*)(Af + (size_t)(row0 + row) * K + col);
        hi = *(const float4*)(Af + (size_t)(row0 + row) * K + col + 4);
      }
      ra[c] = make_uint4(pk2bf(lo.x, lo.y), pk2bf(lo.z, lo.w), pk2bf(hi.x, hi.y), pk2bf(hi.z, hi.w));
    }
  } else {
    const unsigned short* Ab = (const unsigned short*)Av;
#pragma unroll
    for (int c = 0; c < CH; ++c) {
      int ch = c * 256 + tid;
      int row = ch * 8 / K;
      ra[c] = (row0 + row < M) ? *(const uint4*)(Ab + (size_t)row0 * K + ch * 8)
                               : make_uint4(0u, 0u, 0u, 0u);
    }
  }
#pragma unroll
  for (int c = 0; c < CH; ++c) {
    int ch = c * 256 + tid;
    int row = ch * 8 / K;
    int off = ch * 16 - row * (2 * K);
    *(uint4*)((char*)At + row * (2 * K) + (off ^ ((row & SWZ) << 4))) = ra[c];
  }
  __syncthreads();

  f32x4 acc[RS][2];
#pragma unroll
  for (int r = 0; r < RS; ++r)
#pragma unroll
    for (int cf = 0; cf < 2; ++cf) acc[r][cf] = (f32x4){0.f, 0.f, 0.f, 0.f};

  const int rwave = (NC == 128) ? 0 : 32 * wid;
#pragma unroll
  for (int ks = 0; ks < NKS; ++ks) {
#pragma unroll
    for (int r = 0; r < RS; ++r) {
      int row = rwave + 16 * r + l15;
      int off = ks * 64 + g * 16;
      short8 af = *(const short8*)((const char*)At + row * (2 * K) + (off ^ ((row & SWZ) << 4)));
#pragma unroll
      for (int cf = 0; cf < 2; ++cf)
        acc[r][cf] = __builtin_amdgcn_mfma_f32_16x16x32_bf16(wf[ks][cf], af, acc[r][cf], 0, 0, 0);
    }
  }

#pragma unroll
  for (int r = 0; r < RS; ++r) {
    const int row = row0 + rwave + 16 * r + l15;
    const bool ok = row < M;
#pragma unroll
    for (int cf = 0; cf < 2; ++cf) {
      const int colbase = ((NC == 128) ? 32 * wid : 0) + 16 * cf + 4 * g;
      if constexpr (OUT16) {
        if (ok) {
          unsigned short* Cb = (unsigned short*)Cv;
          ushort4 o;
          o.x = f2bf(acc[r][cf][0]); o.y = f2bf(acc[r][cf][1]);
          o.z = f2bf(acc[r][cf][2]); o.w = f2bf(acc[r][cf][3]);
          *(ushort4*)(Cb + (size_t)row * NC + colbase) = o;
        }
      } else if constexpr (RB) {
        if (ok) {
          float* C = (float*)Cv;
          float4 bi = *(const float4*)(bias + colbase);
          float4 rv = *(const float4*)(resid + (size_t)row * NC + colbase);
          float4 o;
          o.x = acc[r][cf][0] + bi.x + rv.x;
          o.y = acc[r][cf][1] + bi.y + rv.y;
          o.z = acc[r][cf][2] + bi.z + rv.z;
          o.w = acc[r][cf][3] + bi.w + rv.w;
          *(float4*)(C + (size_t)row * NC + colbase) = o;
        }
      }
    }
    if constexpr (ALPHA) {
      constexpr int H = NC / 32;
      const int head = (NC == 128) ? wid : 0;
      float ps = 0.f, pd = 0.f;
#pragma unroll
      for (int cf = 0; cf < 2; ++cf) {
        float4 sa = *(const float4*)(a_s + head * 32 + 16 * cf + 4 * g);
        float4 da = *(const float4*)(a_d + head * 32 + 16 * cf + 4 * g);
        ps += acc[r][cf][0] * sa.x + acc[r][cf][1] * sa.y + acc[r][cf][2] * sa.z + acc[r][cf][3] * sa.w;
        pd += acc[r][cf][0] * da.x + acc[r][cf][1] * da.y + acc[r][cf][2] * da.z + acc[r][cf][3] * da.w;
      }
      ps += __shfl_xor(ps, 16, 64); pd += __shfl_xor(pd, 16, 64);
      ps += __shfl_xor(ps, 32, 64); pd += __shfl_xor(pd, 32, 64);
      if (g == 0 && ok) {
        asrc[(size_t)row * H + head] = ps;
        adst[(size_t)row * H + head] = pd;
      }
    }
  }
}

// ---------------- agg for HC=128 (H=4): one wave per node ----------------
template<int ACT>
__global__ __launch_bounds__(256) void agg128_k(const unsigned short* __restrict__ Hb,
                                                const float* __restrict__ asrc,
                                                const float* __restrict__ adst,
                                                const int* __restrict__ deg,
                                                const unsigned short* __restrict__ cols,
                                                const float* __restrict__ bias,
                                                unsigned short* __restrict__ Y, int Nn) {
  __shared__ float wl[4][256];
  __shared__ int sl[4][64];
  const int wid = threadIdx.x >> 6, lane = threadIdx.x & 63;
  const int node = blockIdx.x * 4 + wid;
  if (node >= Nn) return;
  const int eidx = lane >> 2, h4 = lane & 3;
  const float adr = adst[node * 4 + h4];
  const float asr = asrc[node * 4 + h4];
  int cnt = deg[node];
  cnt = cnt > CAP ? CAP : cnt;
  const unsigned short* __restrict__ cl = cols + (size_t)node * CAP;
  float dn = 0.f;
  for (int c0 = 0; c0 < cnt; c0 += 16) {
    int e = c0 + eidx;
    bool valid = e < cnt;
    int s = valid ? (int)cl[e] : 0;
    float w = valid ? __expf(lrelu02(asrc[s * 4 + h4] + adr)) : 0.f;
    wl[wid][e * 4 + h4] = w;
    if (h4 == 0) sl[wid][e] = s * 16;
    dn += w;
  }
  dn += __shfl_xor(dn, 4, 64);
  dn += __shfl_xor(dn, 8, 64);
  dn += __shfl_xor(dn, 16, 64);
  dn += __shfl_xor(dn, 32, 64);
  float wself = __expf(lrelu02(asr + adr));
  dn += wself;
  float inv = 1.f / (dn + 1e-16f);
  float wsinv = wself * inv;
  for (int j = lane; j < cnt * 4; j += 64) wl[wid][j] *= inv;
  float wns = __shfl(wsinv, (lane & 15) >> 2, 64);
  __builtin_amdgcn_wave_barrier();

  const uint4* __restrict__ HB = (const uint4*)Hb;
  const int sub = lane >> 4;
  const int c8 = lane & 15;
  const int h = c8 >> 2;
  float a0 = 0.f, a1 = 0.f, a2 = 0.f, a3 = 0.f, a4 = 0.f, a5 = 0.f, a6 = 0.f, a7 = 0.f;
  float p0 = 0.f, p1 = 0.f, p2 = 0.f, p3 = 0.f, p4 = 0.f, p5 = 0.f, p6 = 0.f, p7 = 0.f;
  int i = sub;
  for (; i + 4 < cnt; i += 8) {
    int o0 = sl[wid][i];
    int o1 = sl[wid][i + 4];
    float w0 = wl[wid][i * 4 + h];
    float w1 = wl[wid][(i + 4) * 4 + h];
    uint4 u0 = HB[o0 + c8];
    uint4 u1 = HB[o1 + c8];
    a0 += w0 * bfl(u0.x); a1 += w0 * bfh(u0.x); a2 += w0 * bfl(u0.y); a3 += w0 * bfh(u0.y);
    a4 += w0 * bfl(u0.z); a5 += w0 * bfh(u0.z); a6 += w0 * bfl(u0.w); a7 += w0 * bfh(u0.w);
    p0 += w1 * bfl(u1.x); p1 += w1 * bfh(u1.x); p2 += w1 * bfl(u1.y); p3 += w1 * bfh(u1.y);
    p4 += w1 * bfl(u1.z); p5 += w1 * bfh(u1.z); p6 += w1 * bfl(u1.w); p7 += w1 * bfh(u1.w);
  }
  for (; i < cnt; i += 4) {
    int o0 = sl[wid][i];
    float w0 = wl[wid][i * 4 + h];
    uint4 u0 = HB[o0 + c8];
    a0 += w0 * bfl(u0.x); a1 += w0 * bfh(u0.x); a2 += w0 * bfl(u0.y); a3 += w0 * bfh(u0.y);
    a4 += w0 * bfl(u0.z); a5 += w0 * bfh(u0.z); a6 += w0 * bfl(u0.w); a7 += w0 * bfh(u0.w);
  }
  a0 += p0; a1 += p1; a2 += p2; a3 += p3; a4 += p4; a5 += p5; a6 += p6; a7 += p7;
#pragma unroll
  for (int off = 16; off <= 32; off <<= 1) {
    a0 += __shfl_xor(a0, off, 64); a1 += __shfl_xor(a1, off, 64);
    a2 += __shfl_xor(a2, off, 64); a3 += __shfl_xor(a3, off, 64);
    a4 += __shfl_xor(a4, off, 64); a5 += __shfl_xor(a5, off, 64);
    a6 += __shfl_xor(a6, off, 64); a7 += __shfl_xor(a7, off, 64);
  }
  if (lane < 16) {
    uint4 us = HB[node * 16 + c8];
    float4 b0 = *(const float4*)(bias + c8 * 8);
    float4 b1 = *(const float4*)(bias + c8 * 8 + 4);
    float o0 = a0 + wns * bfl(us.x) + b0.x;
    float o1 = a1 + wns * bfh(us.x) + b0.y;
    float o2 = a2 + wns * bfl(us.y) + b0.z;
    float o3 = a3 + wns * bfh(us.y) + b0.w;
    float o4 = a4 + wns * bfl(us.z) + b1.x;
    float o5 = a5 + wns * bfh(us.z) + b1.y;
    float o6 = a6 + wns * bfl(us.w) + b1.z;
    float o7 = a7 + wns * bfh(us.w) + b1.w;
    if (ACT == 1) {
      o0 = lrelu01(o0); o1 = lrelu01(o1); o2 = lrelu01(o2); o3 = lrelu01(o3);
      o4 = lrelu01(o4); o5 = lrelu01(o5); o6 = lrelu01(o6); o7 = lrelu01(o7);
    }
    ((uint4*)Y)[(size_t)node * 16 + c8] =
        make_uint4(pk2bf(o0, o1), pk2bf(o2, o3), pk2bf(o4, o5), pk2bf(o6, o7));
  }
}

// ---------------- agg32 core: phase 0+1, returns float4 of channels [4c,4c+4) valid on lanes<8 ----------------
template<int ACT>
__device__ __forceinline__ float4 agg32_core(const unsigned short* __restrict__ Hb,
                                             const float* __restrict__ asrc, const float* __restrict__ adst,
                                             const int* __restrict__ deg,
                                             const unsigned short* __restrict__ cols,
                                             const float* __restrict__ bias,
                                             float (*wl)[64], int (*sl)[64],
                                             int wid, int lane, int node) {
  const float adr = adst[node], asr = asrc[node];
  int cnt = deg[node];
  cnt = cnt > CAP ? CAP : cnt;
  const unsigned short* __restrict__ cl = cols + (size_t)node * CAP;
  int s = (lane < cnt) ? (int)cl[lane] : 0;
  float w = (lane < cnt) ? __expf(lrelu02(asrc[s] + adr)) : 0.f;
  float dn = w;
#pragma unroll
  for (int off = 32; off >= 1; off >>= 1) dn += __shfl_xor(dn, off, 64);
  float ws = __expf(lrelu02(asr + adr));
  dn += ws;
  float inv = 1.f / (dn + 1e-16f);
  wl[wid][lane] = w * inv;
  sl[wid][lane] = s * 8;
  __builtin_amdgcn_wave_barrier();

  const uint2* __restrict__ HB = (const uint2*)Hb;
  const int sub = lane >> 3;
  const int c = lane & 7;
  float a0 = 0.f, a1 = 0.f, a2 = 0.f, a3 = 0.f;
  float p0 = 0.f, p1 = 0.f, p2 = 0.f, p3 = 0.f;
  int i = sub;
  for (; i + 8 < cnt; i += 16) {
    int o0 = sl[wid][i];
    int o1 = sl[wid][i + 8];
    float w0 = wl[wid][i];
    float w1 = wl[wid][i + 8];
    uint2 u0 = HB[o0 + c];
    uint2 u1 = HB[o1 + c];
    a0 += w0 * bfl(u0.x); a1 += w0 * bfh(u0.x); a2 += w0 * bfl(u0.y); a3 += w0 * bfh(u0.y);
    p0 += w1 * bfl(u1.x); p1 += w1 * bfh(u1.x); p2 += w1 * bfl(u1.y); p3 += w1 * bfh(u1.y);
  }
  for (; i < cnt; i += 8) {
    int o0 = sl[wid][i];
    float w0 = wl[wid][i];
    uint2 u0 = HB[o0 + c];
    a0 += w0 * bfl(u0.x); a1 += w0 * bfh(u0.x); a2 += w0 * bfl(u0.y); a3 += w0 * bfh(u0.y);
  }
  a0 += p0; a1 += p1; a2 += p2; a3 += p3;
#pragma unroll
  for (int off = 8; off <= 32; off <<= 1) {
    a0 += __shfl_xor(a0, off, 64); a1 += __shfl_xor(a1, off, 64);
    a2 += __shfl_xor(a2, off, 64); a3 += __shfl_xor(a3, off, 64);
  }
  float4 out = make_float4(0.f, 0.f, 0.f, 0.f);
  if (lane < 8) {
    uint2 us = HB[node * 8 + c];
    float wns = ws * inv;
    float4 bb = ((const float4*)bias)[c];
    out.x = a0 + wns * bfl(us.x) + bb.x;
    out.y = a1 + wns * bfh(us.x) + bb.y;
    out.z = a2 + wns * bfl(us.y) + bb.z;
    out.w = a3 + wns * bfh(us.y) + bb.w;
    if (ACT == 1) { out.x = lrelu01(out.x); out.y = lrelu01(out.y); out.z = lrelu01(out.z); out.w = lrelu01(out.w); }
  }
  return out;
}

// ---------------- agg32-L3 fused (4 nodes/block): z -> zout; h4 = z@Wd (f32, LDS Wd); L4 alphas ----------------
__global__ __launch_bounds__(256) void agg32_l3_k(const unsigned short* __restrict__ Hb,
                                                  const float* __restrict__ asrc, const float* __restrict__ adst,
                                                  const int* __restrict__ deg,
                                                  const unsigned short* __restrict__ cols,
                                                  const float* __restrict__ bl,
                                                  const float* __restrict__ Wd,
                                                  const float* __restrict__ ads, const float* __restrict__ add_,
                                                  float* __restrict__ zout, unsigned short* __restrict__ H4,
                                                  float* __restrict__ asrcB, float* __restrict__ adstB, int Nn) {
  __shared__ float Wd_l[32 * 32];
  __shared__ float wl[4][64];
  __shared__ int sl[4][64];
  __shared__ float zb[4][32];
  {
    int t = threadIdx.x * 4;
    *(float4*)&Wd_l[t] = *(const float4*)(Wd + t);
  }
  __syncthreads();
  const int wid = threadIdx.x >> 6, lane = threadIdx.x & 63;
  const int node = blockIdx.x * 4 + wid;
  if (node >= Nn) return;

  float4 z = agg32_core<0>(Hb, asrc, adst, deg, cols, bl, wl, sl, wid, lane, node);
  const int c = lane & 7;
  if (lane < 8) {
    ((float4*)zout)[(size_t)node * 8 + c] = z;
    *(float4*)&zb[wid][c * 4] = z;
  }
  __builtin_amdgcn_wave_barrier();

  float h4 = 0.f;
  const int j = lane & 31;
#pragma unroll 8
  for (int k = 0; k < 32; ++k) h4 += zb[wid][k] * Wd_l[k * 32 + j];
  float ps = 0.f, pd = 0.f;
  if (lane < 32) {
    H4[(size_t)node * 32 + j] = f2bf(h4);
    ps = h4 * ads[j];
    pd = h4 * add_[j];
  }
#pragma unroll
  for (int off = 1; off <= 16; off <<= 1) { ps += __shfl_xor(ps, off, 64); pd += __shfl_xor(pd, off, 64); }
  if (lane == 0) {
    asrcB[node] = ps;
    adstB[node] = pd;
  }
}

// ---------------- agg32-L4 (plain, 4 nodes/block): gather h4 -> xr (bf16) ----------------
__global__ __launch_bounds__(256) void agg32_l4_k(const unsigned short* __restrict__ Hb,
                                                  const float* __restrict__ asrc, const float* __restrict__ adst,
                                                  const int* __restrict__ deg,
                                                  const unsigned short* __restrict__ cols,
                                                  const float* __restrict__ bd,
                                                  unsigned short* __restrict__ Y, int Nn) {
  __shared__ float wl[4][64];
  __shared__ int sl[4][64];
  const int wid = threadIdx.x >> 6, lane = threadIdx.x & 63;
  const int node = blockIdx.x * 4 + wid;
  if (node >= Nn) return;
  float4 xr = agg32_core<1>(Hb, asrc, adst, deg, cols, bd, wl, sl, wid, lane, node);
  const int c = lane & 7;
  if (lane < 8) {
    ((uint2*)Y)[(size_t)node * 8 + c] = make_uint2(pk2bf(xr.x, xr.y), pk2bf(xr.z, xr.w));
  }
}

extern "C" void kernel_launch(void* const* d_in, const int* in_sizes, int n_in,
                              void* d_out, int out_size, void* d_ws, size_t ws_size,
                              hipStream_t stream) {
  const float* x = (const float*)d_in[0];
  const int* ei = (const int*)d_in[1];
  const float* W1 = (const float*)d_in[2];
  const float* a1s = (const float*)d_in[3];
  const float* a1d = (const float*)d_in[4];
  const float* b1 = (const float*)d_in[5];
  const float* W2 = (const float*)d_in[6];
  const float* a2s = (const float*)d_in[7];
  const float* a2d = (const float*)d_in[8];
  const float* b2 = (const float*)d_in[9];
  const float* Wl = (const float*)d_in[10];
  const float* als = (const float*)d_in[11];
  const float* ald = (const float*)d_in[12];
  const float* bl = (const float*)d_in[13];
  const float* Wd = (const float*)d_in[14];
  const float* ads = (const float*)d_in[15];
  const float* add_ = (const float*)d_in[16];
  const float* bd = (const float*)d_in[17];
  const float* Wdec = (const float*)d_in[18];
  const float* bdec = (const float*)d_in[19];

  const int N = in_sizes[0] / 128;
  const int E = in_sizes[1] / 2;
  const int nr = (N + 7) / 8;

  char* ws = (char*)d_ws;
  auto alloc = [&](size_t bytes) {
    char* p = ws;
    ws += (bytes + 255) & ~(size_t)255;
    return p;
  };
  unsigned short* cols = (unsigned short*)alloc((size_t)N * CAP * 2);
  int* deg = (int*)alloc((size_t)N * 4);
  unsigned short* hb16 = (unsigned short*)alloc((size_t)N * 128 * 2);
  float* asrc = (float*)alloc((size_t)N * 4 * 4);
  float* adst = (float*)alloc((size_t)N * 4 * 4);
  float* asrcB = (float*)alloc((size_t)N * 4);
  float* adstB = (float*)alloc((size_t)N * 4);
  unsigned short* x12 = (unsigned short*)alloc((size_t)N * 128 * 2);  // x1, then x2 (aliased)
  unsigned short* hb2 = (unsigned short*)alloc((size_t)N * 32 * 2);   // h4 (bf16)
  unsigned short* xr16 = (unsigned short*)alloc((size_t)N * 32 * 2);
  unsigned short* W1t = (unsigned short*)alloc(128 * 128 * 2);
  unsigned short* W2t = (unsigned short*)alloc(128 * 128 * 2);
  unsigned short* Wlt = (unsigned short*)alloc(128 * 32 * 2);
  unsigned short* Wdect = (unsigned short*)alloc(32 * 128 * 2);

  float* rec = (float*)d_out;                     // [N,128]
  float* zout = (float*)d_out + (size_t)N * 128;  // [N,32]

  hipMemsetAsync(deg, 0, (size_t)N * 4, stream);
  prep_k<<<2192, 256, 0, stream>>>(ei, deg, cols, E, nr, N, W1, W2, Wl, W1t, W2t, Wlt);

  const int gG128 = (N + 63) / 64;   // BM=64 grids (NC=128)
  const int gG32 = (N + 127) / 128;  // BM=128 grids (NC=32)
  const int gAg = (N + 3) / 4;

  // Wdec transpose (tiny, fold into a 16-block launch appended to the graph)
  // reuse prep-style inline: do it with a small lambda-kernel via cvt of Wdec
  // (16 blocks x 256 thr covers 32*128)
  {
    // small dedicated launch
    struct L { static __global__ void k(const float* __restrict__ src, unsigned short* __restrict__ dst) {
      int e = blockIdx.x * 256 + threadIdx.x;
      if (e < 32 * 128) {
        int k = e / 128, c = e - k * 128;
        dst[c * 32 + k] = f2bf(src[e]);
      }
    } };
    hipLaunchKernelGGL(L::k, dim3(16), dim3(256), 0, stream, Wdec, Wdect);
  }

  // Layer 1: x(fp32, converted in staging) -> h1(bf16) + alphas; agg -> x1(bf16)
  gemm_mfma<128, 128, true, true, false, true><<<gG128, 256, 0, stream>>>(
      x, W1t, nullptr, nullptr, hb16, a1s, a1d, asrc, adst, N);
  agg128_k<1><<<gAg, 256, 0, stream>>>(hb16, asrc, adst, deg, cols, b1, x12, N);

  // Layer 2: x1 -> h2 + alphas; agg -> x2 (in-place over x1)
  gemm_mfma<128, 128, true, true, false, false><<<gG128, 256, 0, stream>>>(
      x12, W2t, nullptr, nullptr, hb16, a2s, a2d, asrc, adst, N);
  agg128_k<1><<<gAg, 256, 0, stream>>>(hb16, asrc, adst, deg, cols, b2, x12, N);

  // Layer 3 (latent): x2 -> h3 + alphas
  gemm_mfma<128, 32, true, true, false, false><<<gG32, 256, 0, stream>>>(
      x12, Wlt, nullptr, nullptr, hb16, als, ald, asrc, adst, N);
  // agg -> z (fp32 to d_out); fused: h4 = z@Wd (f32) + L4 alphas
  agg32_l3_k<<<gAg, 256, 0, stream>>>(hb16, asrc, adst, deg, cols, bl, Wd, ads, add_,
                                      zout, hb2, asrcB, adstB, N);

  // Layer 4: gather h4 -> xr (bf16)
  agg32_l4_k<<<gAg, 256, 0, stream>>>(hb2, asrcB, adstB, deg, cols, bd, xr16, N);

  // Final decode: rec = xr16 @ Wdec + bdec + x  (MFMA)
  gemm_mfma<32, 128, false, false, true, false><<<gG128, 256, 0, stream>>>(
      xr16, Wdect, bdec, x, rec, nullptr, nullptr, nullptr, nullptr, N);
}